// Round 6
// baseline (207.387 us; speedup 1.0000x reference)
//
#include <hip/hip_runtime.h>

#define TT 4096          // signal length
#define NN 8192          // padded length
#define NF 4096          // FFT length = 16^3

// XOR swizzle: permutes low 4 bits by a hash of the row; measured ~2% LDS
// bank-conflict overhead (R4) across all access patterns used here.
#define SW(i) ((i) ^ ((((i) >> 4) ^ ((i) >> 8)) & 15))

// hardware sin/cos of 2*pi*x (x in revolutions); args here are exact dyadics
__device__ __forceinline__ float sin2pi(float x) { return __builtin_amdgcn_sinf(x); }
__device__ __forceinline__ float cos2pi(float x) { return __builtin_amdgcn_cosf(x); }

// -------------------- register DFT16 (two radix-4 layers, DIT) --------------
// S = -1: forward (e^{-i}), S = +1: inverse (e^{+i}).
template<int S>
__device__ __forceinline__ void dft4(float& ar, float& ai, float& br, float& bi,
                                     float& cr, float& ci, float& er, float& ei) {
    float t0r = ar + cr, t0i = ai + ci;
    float t1r = ar - cr, t1i = ai - ci;
    float t2r = br + er, t2i = bi + ei;
    float t3r = br - er, t3i = bi - ei;
    ar = t0r + t2r; ai = t0i + t2i;
    cr = t0r - t2r; ci = t0i - t2i;
    br = t1r - S * t3i; bi = t1i + S * t3r;
    er = t1r + S * t3i; ei = t1i - S * t3r;
}

template<int S>
__device__ __forceinline__ void dft16(float xr[16], float xi[16]) {
    #pragma unroll
    for (int n0 = 0; n0 < 4; ++n0)
        dft4<S>(xr[n0], xi[n0], xr[n0 + 4], xi[n0 + 4],
                xr[n0 + 8], xi[n0 + 8], xr[n0 + 12], xi[n0 + 12]);

    const float C1 = 0.9238795325112867f;   // cos(pi/8)
    const float S1 = 0.3826834323650898f;   // sin(pi/8)
    const float R2 = 0.7071067811865476f;
    #define TMUL(idx, wr, wi) { float _r = xr[idx]*(wr) - xi[idx]*(wi); \
                                xi[idx] = xr[idx]*(wi) + xi[idx]*(wr); xr[idx] = _r; }
    TMUL(5,  C1,  S * S1)
    TMUL(9,  R2,  S * R2)
    TMUL(13, S1,  S * C1)
    TMUL(6,  R2,  S * R2)
    { float _r = -S * xi[10]; xi[10] = S * xr[10]; xr[10] = _r; }
    TMUL(14, -R2, S * R2)
    TMUL(7,  S1,  S * C1)
    TMUL(11, -R2, S * R2)
    TMUL(15, -C1, -S * S1)
    #undef TMUL

    #pragma unroll
    for (int k0 = 0; k0 < 4; ++k0)
        dft4<S>(xr[4*k0], xi[4*k0], xr[4*k0+1], xi[4*k0+1],
                xr[4*k0+2], xi[4*k0+2], xr[4*k0+3], xi[4*k0+3]);

    float tr[16], ti[16];
    #pragma unroll
    for (int q = 0; q < 16; ++q) { int p = 4*(q & 3) + (q >> 2); tr[q] = xr[p]; ti[q] = xi[p]; }
    #pragma unroll
    for (int q = 0; q < 16; ++q) { xr[q] = tr[q]; xi[q] = ti[q]; }
}

// apply W^q (q=1..15) to x[q] by chained complex mul from W^1 = (w1r, w1i)
__device__ __forceinline__ void twiddle_chain(float xr[16], float xi[16],
                                              float w1r, float w1i) {
    float cwr = w1r, cwi = w1i;
    #pragma unroll
    for (int q = 1; q < 16; ++q) {
        float r = xr[q] * cwr - xi[q] * cwi;
        xi[q] = xr[q] * cwi + xi[q] * cwr;
        xr[q] = r;
        if (q < 15) {
            float nr = cwr * w1r - cwi * w1i;
            cwi = cwr * w1i + cwi * w1r;
            cwr = nr;
        }
    }
}

// ==================== single-signal FFT (fwd kernel) =========================
template<int S>
__device__ void fft4096_r16(float2* lds, int tid) {
    float xr[16], xi[16];

    #pragma unroll
    for (int q = 0; q < 16; ++q) {
        float2 v = lds[SW(tid + 256 * q)];
        xr[q] = v.x; xi[q] = v.y;
    }
    dft16<S>(xr, xi);
    {
        const float t = (float)tid * (1.0f / 4096.0f);
        twiddle_chain(xr, xi, cos2pi(t), S * sin2pi(t));
    }
    #pragma unroll
    for (int q = 0; q < 16; ++q) lds[SW(tid + 256 * q)] = make_float2(xr[q], xi[q]);
    __syncthreads();

    {
        const int j = tid & 15;
        const int base = ((tid >> 4) << 8) + j;
        #pragma unroll
        for (int q = 0; q < 16; ++q) {
            float2 v = lds[SW(base + 16 * q)];
            xr[q] = v.x; xi[q] = v.y;
        }
        dft16<S>(xr, xi);
        const float t = (float)j * (1.0f / 256.0f);
        twiddle_chain(xr, xi, cos2pi(t), S * sin2pi(t));
        #pragma unroll
        for (int q = 0; q < 16; ++q) lds[SW(base + 16 * q)] = make_float2(xr[q], xi[q]);
    }
    __syncthreads();

    {
        const int base = tid << 4;
        const int f2 = (tid ^ (tid >> 4)) & 15;
        #pragma unroll
        for (int q = 0; q < 16; ++q) {
            float2 v = lds[base + (q ^ f2)];
            xr[q] = v.x; xi[q] = v.y;
        }
        dft16<S>(xr, xi);
        __syncthreads();
        const int c = tid & 15;
        const int h = tid >> 4;
        #pragma unroll
        for (int q = 0; q < 16; ++q)
            lds[(q << 8) + (c << 4) + (h ^ c ^ q)] = make_float2(xr[q], xi[q]);
    }
    __syncthreads();
}

__device__ __forceinline__ int refl(int p) {
    if (p < 2048) return 2047 - p;
    if (p < 6144) return p - 2048;
    return 10239 - p;
}

// -------------------- forward: real-8192 FFT via packed complex-4096 ---------
__global__ __launch_bounds__(256) void fwd_kernel(const float* __restrict__ in,
                                                  float2* __restrict__ F) {
    __shared__ float2 lds[NF];
    const int b = blockIdx.x, tid = threadIdx.x;
    const float* row = in + b * TT;

    for (int i = tid; i < NF; i += 256)
        lds[SW(i)] = make_float2(row[refl(2 * i)], row[refl(2 * i + 1)]);
    __syncthreads();

    fft4096_r16<-1>(lds, tid);

    for (int i = tid; i < NF; i += 256) {
        const int k = i + 1;
        const float2 za = lds[SW(k & (NF - 1))];
        const float2 zb = lds[SW((NF - k) & (NF - 1))];
        const float fer = 0.5f * (za.x + zb.x), fei = 0.5f * (za.y - zb.y);
        const float fo_r = 0.5f * (za.y + zb.y), fo_i = -0.5f * (za.x - zb.x);
        const float t = (float)k * (1.0f / 8192.0f);
        const float c = cos2pi(t), s = sin2pi(t);   // tw = (c, -s)
        F[b * NF + i] = make_float2(fer + c * fo_r + s * fo_i,
                                    fei + c * fo_i - s * fo_r);
    }
}

// -------------------- inverse: one block per (batch, scale) ------------------
// d_k = F[b,k]*wft[j,k+1]; half-band 8192-IFFT = two 4096-IFFTs (even/odd
// output samples). 512 threads: waves 0-3 transform signal 0 (even), waves
// 4-7 signal 1 (odd) in separate dense 32 KB LDS planes. One dft16 per
// thread per stage -> 4 waves/SIMD at 2 blocks/CU.
__global__ __launch_bounds__(512) void inv_kernel(const float2* __restrict__ F,
                                                  const float* __restrict__ wft,
                                                  float* __restrict__ out,
                                                  int NS) {
    __shared__ float2 lds2[2][NF];              // 64 KB total
    const int blk = blockIdx.x;
    const int b = blk / NS;
    const int j = blk - b * NS;
    const int tid = threadIdx.x;
    const int s = tid >> 8;                     // signal select (wave-uniform)
    const int g = tid & 255;                    // group index within signal

    const float2* Frow = F + b * NF;
    const float* wrow = wft + (size_t)j * NN + 1;
    float* orow = out + (size_t)(b * NS + j) * TT;
    const float LOGN = 9.0109131020007136f;       // log(8192)
    const float HALF_LN2 = 0.34657359027997264f;  // 0.5 * ln(2)

    // ---- staging: 8 k's per thread; d0 = F*w -> plane0, d1 = d0*cis(k/8192)
    // ---- -> plane1. Phase via recurrence: step cis(512/8192) = cis(1/16).
    {
        const float t0 = (float)tid * (1.0f / 8192.0f);
        float cr = cos2pi(t0), ci = sin2pi(t0);
        const float KR = 0.9238795325112867f;   // cos(2pi/16)
        const float KI = 0.3826834323650898f;   // sin(2pi/16)
        #pragma unroll
        for (int r = 0; r < 8; ++r) {
            const int k = tid + 512 * r;
            const float2 f = Frow[k];
            const float w = wrow[k];
            const float d0r = f.x * w, d0i = f.y * w;
            lds2[0][SW(k)] = make_float2(d0r, d0i);
            lds2[1][SW(k)] = make_float2(d0r * cr - d0i * ci,
                                         d0r * ci + d0i * cr);
            float nr = cr * KR - ci * KI;
            ci = cr * KI + ci * KR;
            cr = nr;
        }
    }
    __syncthreads();

    float2* lds = lds2[s];
    float xr[16], xi[16];

    // ---- stage 0: stride 256, group g, twiddle W_4096^{g*q} (inverse) ----
    #pragma unroll
    for (int q = 0; q < 16; ++q) {
        float2 v = lds[SW(g + 256 * q)];
        xr[q] = v.x; xi[q] = v.y;
    }
    dft16<1>(xr, xi);
    {
        const float t = (float)g * (1.0f / 4096.0f);
        twiddle_chain(xr, xi, cos2pi(t), sin2pi(t));    // S=+1
    }
    #pragma unroll
    for (int q = 0; q < 16; ++q) lds[SW(g + 256 * q)] = make_float2(xr[q], xi[q]);
    __syncthreads();

    // ---- stage 1: stride 16, j1 = g&15, twiddle W_256^{j1*q} ----
    {
        const int j1 = g & 15;
        const int base = ((g >> 4) << 8) + j1;
        #pragma unroll
        for (int q = 0; q < 16; ++q) {
            float2 v = lds[SW(base + 16 * q)];
            xr[q] = v.x; xi[q] = v.y;
        }
        dft16<1>(xr, xi);
        const float t = (float)j1 * (1.0f / 256.0f);
        twiddle_chain(xr, xi, cos2pi(t), sin2pi(t));
        #pragma unroll
        for (int q = 0; q < 16; ++q) lds[SW(base + 16 * q)] = make_float2(xr[q], xi[q]);
    }
    __syncthreads();

    // ---- stage 2: 16 contiguous points, twiddle-free; scatter natural ----
    {
        const int base = g << 4;
        const int f2 = (g ^ (g >> 4)) & 15;
        #pragma unroll
        for (int q = 0; q < 16; ++q) {
            float2 v = lds[base + (q ^ f2)];
            xr[q] = v.x; xi[q] = v.y;
        }
        dft16<1>(xr, xi);
        __syncthreads();
        const int c = g & 15;
        const int h = g >> 4;
        #pragma unroll
        for (int q = 0; q < 16; ++q)
            lds[(q << 8) + (c << 4) + (h ^ c ^ q)] = make_float2(xr[q], xi[q]);
    }
    __syncthreads();

    // ---- epilogue: central half, t_global = 2*tp + s, out idx = 2*(tp-1024)+s
    #pragma unroll
    for (int i2 = 0; i2 < 8; ++i2) {
        const int tp = 1024 + g + 256 * i2;
        const float2 z = lds[SW(tp)];
        const float m = z.x * z.x + z.y * z.y;
        orow[((tp - 1024) << 1) + s] = HALF_LN2 * __builtin_amdgcn_logf(m) - LOGN;
    }
}

extern "C" void kernel_launch(void* const* d_in, const int* in_sizes, int n_in,
                              void* d_out, int out_size, void* d_ws, size_t ws_size,
                              hipStream_t stream) {
    const float* inputs = (const float*)d_in[0];
    const float* wft = (const float*)d_in[1];
    float* out = (float*)d_out;

    const int B = in_sizes[0] / TT;     // 64
    const int NS = in_sizes[1] / NN;    // 75

    float2* F = (float2*)d_ws;          // B*4096 complex = 2 MB

    hipLaunchKernelGGL(fwd_kernel, dim3(B), dim3(256), 0, stream, inputs, F);
    hipLaunchKernelGGL(inv_kernel, dim3(B * NS), dim3(512), 0, stream, F, wft, out, NS);
}